// Round 4
// baseline (495.948 us; speedup 1.0000x reference)
//
#include <hip/hip_runtime.h>

// ---------------------------------------------------------------------------
// Attention_49185965474367: B=4, N=1024, D=1024, H=16, DH=64, INNER=1024
// R6: swapped-operand QK^T (s = mfma(K,Q)) so softmax reduction is thread-local
//     (15 reg-ops + 2 shuffles vs 32-shuffle storm), float4 rel loads, additive
//     rbias context-mask, ushort4 P-writes, defer-max (THR=8). K via dbuf
//     LDS-DMA (R5), V reg-hoisted, rel reg-dbuf. GEMMs unchanged.
// ---------------------------------------------------------------------------

#define NEGMAX 3.402823466e+38f

typedef short short8 __attribute__((ext_vector_type(8)));
typedef float f32x4 __attribute__((ext_vector_type(4)));

__device__ __forceinline__ unsigned short f2bf(float f) {
  unsigned int u = __float_as_uint(f);
  u += 0x7FFFu + ((u >> 16) & 1u);   // round-to-nearest-even
  return (unsigned short)(u >> 16);
}

// async global->LDS, 16B per lane. lds_base must be wave-uniform; HW scatters
// lane i to lds_base + i*16. Global src addr IS per-lane (guide §5).
__device__ __forceinline__ void stage16(const void* g, void* lds_base, int lane) {
#if __has_builtin(__builtin_amdgcn_global_load_lds)
  __builtin_amdgcn_global_load_lds(
      (const __attribute__((address_space(1))) unsigned int*)g,
      (__attribute__((address_space(3))) unsigned int*)lds_base, 16, 0, 0);
#else
  *(int4*)((char*)lds_base + lane * 16) = *(const int4*)g;
#endif
}

// ---------------- cast kernels ---------------------------------------------
__global__ void cast_x_k(const float* __restrict__ x, unsigned short* __restrict__ xb) {
  int i = (blockIdx.x * 256 + threadIdx.x) * 4;
  float4 v = *(const float4*)(x + i);
  ushort4 o;
  o.x = f2bf(v.x); o.y = f2bf(v.y); o.z = f2bf(v.z); o.w = f2bf(v.w);
  *(ushort4*)(xb + i) = o;
}

// dst[n][d] = src[d][n]  (src fp32 [1024 x ldsrc], dst bf16 rows of 1024)
__global__ __launch_bounds__(256) void tcast_k(const float* __restrict__ src, int ldsrc,
                                               unsigned short* __restrict__ dst) {
  __shared__ float T[64][65];
  const int n0 = blockIdx.x * 64, d0 = blockIdx.y * 64;
  const int tx = threadIdx.x & 63, ty = threadIdx.x >> 6;
#pragma unroll
  for (int k = 0; k < 16; ++k) {
    int dl = k * 4 + ty;
    T[dl][tx] = src[(size_t)(d0 + dl) * ldsrc + n0 + tx];
  }
  __syncthreads();
#pragma unroll
  for (int k = 0; k < 16; ++k) {
    int nl = k * 4 + ty;
    dst[(size_t)(n0 + nl) * 1024 + d0 + tx] = f2bf(T[tx][nl]);
  }
}

// ---------------- GEMM: C[M,N] = A[M,K] @ Bt[N,K]^T  (bf16 in, fp32 acc) ---
// 128x128 tile, BK=32, 256 threads (4 waves), global_load_lds staging (m97).
// QKV projection with scattered head-layout epilogue.
__global__ __launch_bounds__(256) void gemm_bt_k(
    const unsigned short* __restrict__ A, const unsigned short* __restrict__ Bt,
    unsigned short* __restrict__ qws, unsigned short* __restrict__ kws,
    unsigned short* __restrict__ vtws) {
  constexpr int K = 1024;
  constexpr int NKB = K / 32;
  __shared__ alignas(16) unsigned short As[128 * 32];
  __shared__ alignas(16) unsigned short Bs[128 * 32];
  const int tid = threadIdx.x;
  const int lane = tid & 63, w = tid >> 6;
  const int quad = lane >> 4, lanelo = lane & 15;
  const int tRow = blockIdx.y * 128, tCol = blockIdx.x * 128;
  const int wr = (w >> 1) * 64, wc = (w & 1) * 64;
  const char* AgB = (const char*)(A + (size_t)tRow * K);
  const char* BgB = (const char*)(Bt + (size_t)tCol * K);
  const int c0 = tid, c1 = tid + 256;
  const size_t a0off = (size_t)(c0 >> 2) * 2048 + (c0 & 3) * 16;
  const size_t a1off = (size_t)(c1 >> 2) * 2048 + (c1 & 3) * 16;
  char* ldsA0 = (char*)As + w * 1024;
  char* ldsA1 = (char*)As + 4096 + w * 1024;
  char* ldsB0 = (char*)Bs + w * 1024;
  char* ldsB1 = (char*)Bs + 4096 + w * 1024;

  f32x4 acc[4][4];
#pragma unroll
  for (int i = 0; i < 4; ++i)
#pragma unroll
    for (int j = 0; j < 4; ++j) acc[i][j] = (f32x4){0.f, 0.f, 0.f, 0.f};

  for (int kb = 0; kb < NKB; ++kb) {
    if (kb) __syncthreads();
    const size_t ko = (size_t)kb * 64;
    stage16(AgB + a0off + ko, ldsA0, lane);
    stage16(AgB + a1off + ko, ldsA1, lane);
    stage16(BgB + a0off + ko, ldsB0, lane);
    stage16(BgB + a1off + ko, ldsB1, lane);
    __syncthreads();   // drains vmcnt before any frag read

    short8 af[4], bf[4];
#pragma unroll
    for (int i = 0; i < 4; ++i)
      af[i] = *(const short8*)(As + (wr + i * 16 + lanelo) * 32 + quad * 8);
#pragma unroll
    for (int j = 0; j < 4; ++j)
      bf[j] = *(const short8*)(Bs + (wc + j * 16 + lanelo) * 32 + quad * 8);
#pragma unroll
    for (int i = 0; i < 4; ++i)
#pragma unroll
      for (int j = 0; j < 4; ++j)
        acc[i][j] = __builtin_amdgcn_mfma_f32_16x16x32_bf16(af[i], bf[j], acc[i][j], 0, 0, 0);
  }

#pragma unroll
  for (int i = 0; i < 4; ++i) {
    int row = tRow + wr + i * 16 + quad * 4;
    int b_ = row >> 10;
    int npos = row & 1023;
#pragma unroll
    for (int j = 0; j < 4; ++j) {
      int col = tCol + wc + j * 16 + lanelo;
      if (col < 2048) {
        unsigned short* dst = (col < 1024) ? qws : kws;
        int c = col & 1023;
        int hh = c >> 6, dh = c & 63;
        size_t base = ((size_t)(b_ * 16 + hh) * 1024 + npos) * 64 + dh;
#pragma unroll
        for (int r = 0; r < 4; ++r) dst[base + (size_t)r * 64] = f2bf(acc[i][j][r]);
      } else {
        int c = col - 2048;
        ushort4 pk;
        pk.x = f2bf(acc[i][j][0]);
        pk.y = f2bf(acc[i][j][1]);
        pk.z = f2bf(acc[i][j][2]);
        pk.w = f2bf(acc[i][j][3]);
        *(ushort4*)&vtws[((size_t)(b_ * 16 + (c >> 6)) * 64 + (c & 63)) * 1024 + npos] = pk;
      }
    }
  }
}

// ---------------- GEMM 64x64: C = A @ Bt^T + bias  (out projection) --------
// 1024 blocks (4/CU), 256 thr = 4 waves; wave w owns rows [w*16, w*16+16).
__global__ __launch_bounds__(256) void gemm64_k(
    const unsigned short* __restrict__ A, const unsigned short* __restrict__ Bt,
    const float* __restrict__ bias, float* __restrict__ Cout) {
  constexpr int K = 1024;
  constexpr int NKB = K / 32;
  __shared__ alignas(16) unsigned short As[64 * 32];
  __shared__ alignas(16) unsigned short Bs[64 * 32];
  const int tid = threadIdx.x;
  const int lane = tid & 63, w = tid >> 6;
  const int quad = lane >> 4, lanelo = lane & 15;
  const int tRow = blockIdx.y * 64, tCol = blockIdx.x * 64;
  const char* AgB = (const char*)(A + (size_t)tRow * K);
  const char* BgB = (const char*)(Bt + (size_t)tCol * K);
  const size_t aoff = (size_t)(tid >> 2) * 2048 + (tid & 3) * 16;
  char* ldsA = (char*)As + w * 1024;
  char* ldsB = (char*)Bs + w * 1024;

  f32x4 acc[4];
#pragma unroll
  for (int j = 0; j < 4; ++j) acc[j] = (f32x4){0.f, 0.f, 0.f, 0.f};

  for (int kb = 0; kb < NKB; ++kb) {
    if (kb) __syncthreads();
    const size_t ko = (size_t)kb * 64;
    stage16(AgB + aoff + ko, ldsA, lane);
    stage16(BgB + aoff + ko, ldsB, lane);
    __syncthreads();

    short8 af = *(const short8*)(As + (w * 16 + lanelo) * 32 + quad * 8);
#pragma unroll
    for (int j = 0; j < 4; ++j) {
      short8 bf = *(const short8*)(Bs + (j * 16 + lanelo) * 32 + quad * 8);
      acc[j] = __builtin_amdgcn_mfma_f32_16x16x32_bf16(af, bf, acc[j], 0, 0, 0);
    }
  }

  const int row = tRow + w * 16 + quad * 4;
#pragma unroll
  for (int j = 0; j < 4; ++j) {
    int col = tCol + j * 16 + lanelo;
    float bv = bias[col];
#pragma unroll
    for (int r = 0; r < 4; ++r)
      Cout[(size_t)(row + r) * 1024 + col] = acc[j][r] + bv;
  }
}

// ---------------- flash attention, swapped QK^T + thread-local softmax ------
// grid (16, 64) XCD-swizzled (8 bh per XCD -> K/V L2-resident).
// s = mfma(K,Q): thread holds S[16 keys][qrow=lanelo] -> row reduce is 15
// reg-ops + 2 shuffles. cmask as additive rbias (LDS, broadcast reads).
// K via dbuf LDS-DMA (1 barrier/tile); V reg-hoisted; rel reg-dbuf float4.
// Defer-max (THR=8): skip o-rescale while max growth <= 8.
__global__ __launch_bounds__(256)
__attribute__((amdgpu_waves_per_eu(4, 4)))
void attn_k(
    const unsigned short* __restrict__ q_ws, const unsigned short* __restrict__ k_ws,
    const unsigned short* __restrict__ vt_ws, const float* __restrict__ rel,
    const int* __restrict__ qmask, const int* __restrict__ cmask,
    unsigned short* __restrict__ aout) {
  constexpr float SCALE = 0.125f;  // 64^-0.5
  __shared__ alignas(16) unsigned short Kl[2 * 64 * 64];   // 2 x 8KB (DMA dest)
  __shared__ alignas(16) unsigned short Pl[4 * 16 * 72];
  __shared__ float rbias[1024];

  const int tid = threadIdx.x;
  const int w = tid >> 6, lane = tid & 63;
  const int quad = lane >> 4, lanelo = lane & 15;

  // XCD swizzle: flat in [0,1024); virt = (flat%8)*128 + flat/8 (bijective).
  const int flat = blockIdx.y * 16 + blockIdx.x;
  const int virt = (flat & 7) * 128 + (flat >> 3);
  const int bh = virt >> 4, qblk = virt & 15;
  const int b_ = bh >> 4, h = bh & 15;
  const int qrow0 = qblk * 64 + w * 16;

  const unsigned short* kg = k_ws + (size_t)bh * 65536;
  const unsigned short* vg = vt_ws + (size_t)bh * 65536;
  const float* relg = rel + ((size_t)bh * 1024 + qrow0) * 1024;
  unsigned short* pw = Pl + w * 16 * 72;

  // K DMA: LDS[row][p] = global[row][p ^ (row&7)]; read undoes the XOR.
  const int srow = lane >> 3;
  const int spx = (((lane & 7) ^ srow) << 4);
#define STAGE_K(buf, key0n)                                                     \
  {                                                                             \
    _Pragma("unroll")                                                           \
    for (int i_ = 0; i_ < 2; ++i_) {                                            \
      int row_ = w * 16 + i_ * 8 + srow;                                        \
      stage16((const char*)kg + (size_t)((key0n) + row_) * 128 + spx,           \
              (char*)Kl + (buf) * 8192 + w * 2048 + i_ * 1024, lane);           \
    }                                                                           \
  }

  STAGE_K(0, 0);   // K[0] -> buf0

  // additive context-mask bias
  for (int i = tid; i < 1024; i += 256)
    rbias[i] = (cmask[b_ * 1024 + i] != 0) ? 0.f : -NEGMAX;

  const unsigned short* qg = q_ws + ((size_t)bh * 1024 + qrow0) * 64;
  short8 qf0 = *(const short8*)(qg + (size_t)lanelo * 64 + quad * 8);
  short8 qf1 = *(const short8*)(qg + (size_t)lanelo * 64 + 32 + quad * 8);

  const bool qok = qmask[b_ * 1024 + qrow0 + lanelo] != 0;  // this thread's q-row

  f32x4 o[4];
#pragma unroll
  for (int g = 0; g < 4; ++g) o[g] = (f32x4){0.f, 0.f, 0.f, 0.f};
  float m_run = -NEGMAX, l_run = 0.f;

  // rel prefetch for kb=0: row = lanelo, keys quad*4 + 4c + r  -> float4
  f32x4 rl[4];
#pragma unroll
  for (int c = 0; c < 4; ++c)
    rl[c] = *(const f32x4*)(relg + (size_t)lanelo * 1024 + c * 16 + quad * 4);

  const int sb = lanelo & 7;   // K read-swizzle key

  for (int kb = 0; kb < 16; ++kb) {
    const int key0 = kb * 64;
    const int cur = kb & 1;

    __syncthreads();               // K[kb] DMA done; WAR on Kl[cur^1] closed
    if (kb + 1 < 16) STAGE_K(cur ^ 1, key0 + 64);

    // V frags for this tile (cover = QK + softmax)
    short8 vf[8];
#pragma unroll
    for (int c2 = 0; c2 < 2; ++c2)
#pragma unroll
      for (int g = 0; g < 4; ++g)
        vf[c2 * 4 + g] = *(const short8*)(vg + (size_t)(g * 16 + lanelo) * 1024 +
                                          key0 + c2 * 32 + quad * 8);

    // S^T = K Q^T: s[c][r] = S[key = key0 + c*16 + quad*4 + r][qrow = lanelo]
    f32x4 s[4];
#pragma unroll
    for (int c = 0; c < 4; ++c) {
      const char* kbase = (const char*)Kl + cur * 8192 + (c * 16 + lanelo) * 128;
      short8 kfa = *(const short8*)(kbase + ((quad ^ sb) << 4));
      short8 kfb = *(const short8*)(kbase + (((4 + quad) ^ sb) << 4));
      s[c] = (f32x4){0.f, 0.f, 0.f, 0.f};
      s[c] = __builtin_amdgcn_mfma_f32_16x16x32_bf16(kfa, qf0, s[c], 0, 0, 0);
      s[c] = __builtin_amdgcn_mfma_f32_16x16x32_bf16(kfb, qf1, s[c], 0, 0, 0);
    }

    // prefetch next tile's rel (used next iteration)
    f32x4 rln[4];
    if (kb + 1 < 16) {
#pragma unroll
      for (int c = 0; c < 4; ++c)
        rln[c] = *(const f32x4*)(relg + (size_t)lanelo * 1024 + key0 + 64 + c * 16 + quad * 4);
    }

    // masked scores (thread-local row): x in s[], max in-register
    float mloc = -NEGMAX;
#pragma unroll
    for (int c = 0; c < 4; ++c) {
      f32x4 rb = *(const f32x4*)(rbias + key0 + c * 16 + quad * 4);  // broadcast
#pragma unroll
      for (int r = 0; r < 4; ++r) {
        float v = s[c][r] * SCALE + rl[c][r] + rb[r];
        v = qok ? v : -NEGMAX;
        s[c][r] = v;
        mloc = fmaxf(mloc, v);
      }
    }
    mloc = fmaxf(mloc, __shfl_xor(mloc, 16));
    mloc = fmaxf(mloc, __shfl_xor(mloc, 32));

    // defer-max (THR=8): rescale only when max grew past threshold
    if (!__all(mloc - m_run <= 8.f)) {
      float mnew = fmaxf(m_run, mloc);
      float alpha = __expf(m_run - mnew);
      m_run = mnew;
      l_run *= alpha;
      float a4[4];
#pragma unroll
      for (int r = 0; r < 4; ++r) a4[r] = __shfl(alpha, quad * 4 + r, 16);
#pragma unroll
      for (int g = 0; g < 4; ++g)
#pragma unroll
        for (int r = 0; r < 4; ++r) o[g][r] *= a4[r];
    }

    float ps = 0.f;
#pragma unroll
    for (int c = 0; c < 4; ++c) {
      ushort4 pk;
      float p0 = __expf(s[c][0] - m_run);
      float p1 = __expf(s[c][1] - m_run);
      float p2 = __expf(s[c][2] - m_run);
      float p3 = __expf(s[c][3] - m_run);
      ps += (p0 + p1) + (p2 + p3);
      pk.x = f2bf(p0); pk.y = f2bf(p1); pk.z = f2bf(p2); pk.w = f2bf(p3);
      // P[qrow=lanelo][key0 + c*16 + quad*4 .. +3]
      *(ushort4*)((char*)pw + lanelo * 144 + c * 32 + quad * 8) = pk;
    }
    ps += __shfl_xor(ps, 16);
    ps += __shfl_xor(ps, 32);
    l_run += ps;

    // P (A-layout from per-wave Pl) @ V, two k=32 chunks
#pragma unroll
    for (int c2 = 0; c2 < 2; ++c2) {
      short8 pa = *(const short8*)((const char*)pw + lanelo * 144 + c2 * 64 + quad * 16);
#pragma unroll
      for (int g = 0; g < 4; ++g)
        o[g] = __builtin_amdgcn_mfma_f32_16x16x32_bf16(pa, vf[c2 * 4 + g], o[g], 0, 0, 0);
    }

    if (kb + 1 < 16) {
#pragma unroll
      for (int c = 0; c < 4; ++c) rl[c] = rln[c];
    }
  }
#undef STAGE_K

  // epilogue: per-thread l is for qrow=lanelo; fetch for qrow=quad*4+r
  float invl = 1.f / l_run;
#pragma unroll
  for (int r = 0; r < 4; ++r) {
    float iv = __shfl(invl, quad * 4 + r, 16);
    size_t row = (size_t)(b_ * 1024 + qrow0 + quad * 4 + r) * 1024;
#pragma unroll
    for (int g = 0; g < 4; ++g)
      aout[row + h * 64 + g * 16 + lanelo] = f2bf(o[g][r] * iv);
  }
}

// ---------------- launch ----------------------------------------------------
extern "C" void kernel_launch(void* const* d_in, const int* in_sizes, int n_in,
                              void* d_out, int out_size, void* d_ws, size_t ws_size,
                              hipStream_t stream) {
  const float* x = (const float*)d_in[0];
  const float* rel = (const float*)d_in[1];
  const int* qmask = (const int*)d_in[2];
  const int* cmask = (const int*)d_in[3];
  const float* Wq = (const float*)d_in[4];
  const float* Wkv = (const float*)d_in[5];
  const float* Wo = (const float*)d_in[6];
  const float* bo = (const float*)d_in[7];
  float* out = (float*)d_out;

  char* ws = (char*)d_ws;
  const size_t MB = 1024 * 1024;
  unsigned short* w3t = (unsigned short*)(ws);            // 3072x1024 bf16 (6 MB)
  unsigned short* wot = (unsigned short*)(ws + 6 * MB);   // 1024x1024 bf16 (2 MB)
  unsigned short* xb  = (unsigned short*)(ws + 8 * MB);   // 4096x1024 bf16 (8 MB)
  unsigned short* qws = (unsigned short*)(ws + 16 * MB);  // [bh][n][64] (8 MB)
  unsigned short* kws = (unsigned short*)(ws + 24 * MB);  // 8 MB
  unsigned short* vtws = (unsigned short*)(ws + 32 * MB); // [bh][dh][n] (8 MB)
  unsigned short* aout = xb;  // reuse: x dead after QKV GEMM

  cast_x_k<<<4096, 256, 0, stream>>>(x, xb);
  tcast_k<<<dim3(16, 16), 256, 0, stream>>>(Wq, 1024, w3t);
  tcast_k<<<dim3(32, 16), 256, 0, stream>>>(Wkv, 2048, w3t + (size_t)1024 * 1024);
  tcast_k<<<dim3(16, 16), 256, 0, stream>>>(Wo, 1024, wot);
  gemm_bt_k<<<dim3(24, 32), 256, 0, stream>>>(xb, w3t, qws, kws, vtws);
  attn_k<<<dim3(16, 64), 256, 0, stream>>>(qws, kws, vtws, rel, qmask, cmask, aout);
  gemm64_k<<<dim3(16, 64), 256, 0, stream>>>(aout, wot, bo, out);
}